// Round 10
// baseline (1421.596 us; speedup 1.0000x reference)
//
#include <hip/hip_runtime.h>
#include <hip/hip_bf16.h>
#include <cstdint>
#include <cstddef>

#define NN 50000
#define NE 300000
#define BN_EPS 1e-5f
#define USE_GLL 1

typedef unsigned short ushort_t;
typedef __attribute__((ext_vector_type(8))) short short8;
typedef __attribute__((ext_vector_type(4))) float f32x4;

__device__ __forceinline__ float bf_to_f(ushort_t u) {
    union { unsigned int i; float f; } c; c.i = ((unsigned int)u) << 16; return c.f;
}
__device__ __forceinline__ ushort_t f_to_bf(float f) {
    union { unsigned int i; float f; } c; c.f = f;
    unsigned int r = c.i + 0x7FFF + ((c.i >> 16) & 1);
    return (ushort_t)(r >> 16);
}
__device__ __forceinline__ void from_f(float& d, float v) { d = v; }
__device__ __forceinline__ void from_f(ushort_t& d, float v) { d = f_to_bf(v); }

// ---------------- degree count ----------------
__global__ void deg_kernel(const int* __restrict__ dst, int* __restrict__ deg, int E) {
    int e = blockIdx.x * blockDim.x + threadIdx.x;
    if (e < E) atomicAdd(&deg[dst[e]], 1);
}

// ---------------- 3-phase device-wide exclusive scan ----------------
__global__ void scan_reduce(const int* __restrict__ deg, int* __restrict__ bsum,
                            float* __restrict__ dis, int n) {
    int tid = threadIdx.x;
    int idx = blockIdx.x * 256 + tid;
    int v = (idx < n) ? deg[idx] : 0;
    if (idx < n) dis[idx] = rsqrtf((float)v + 1.0f);
    __shared__ int sh[256];
    sh[tid] = v;
    __syncthreads();
    #pragma unroll
    for (int off = 128; off > 0; off >>= 1) {
        if (tid < off) sh[tid] += sh[tid + off];
        __syncthreads();
    }
    if (tid == 0) bsum[blockIdx.x] = sh[0];
}

__global__ void scan_offsets(const int* __restrict__ bsum, int* __restrict__ boff,
                             int* __restrict__ rowstart, int nb, int n) {
    __shared__ int sh[256];
    int tid = threadIdx.x;
    int v = (tid < nb) ? bsum[tid] : 0;
    sh[tid] = v;
    __syncthreads();
    #pragma unroll
    for (int off = 1; off < 256; off <<= 1) {
        int t = (tid >= off) ? sh[tid - off] : 0;
        __syncthreads();
        sh[tid] += t;
        __syncthreads();
    }
    if (tid < nb) boff[tid] = sh[tid] - v;   // exclusive
    if (tid == nb - 1) rowstart[n] = sh[tid];
}

__global__ void scan_final(const int* __restrict__ deg, const int* __restrict__ boff,
                           int* __restrict__ rowstart, int n) {
    int tid = threadIdx.x;
    int idx = blockIdx.x * 256 + tid;
    int v = (idx < n) ? deg[idx] : 0;
    __shared__ int sh[256];
    sh[tid] = v;
    __syncthreads();
    #pragma unroll
    for (int off = 1; off < 256; off <<= 1) {
        int t = (tid >= off) ? sh[tid - off] : 0;
        __syncthreads();
        sh[tid] += t;
        __syncthreads();
    }
    if (idx < n) rowstart[idx] = boff[blockIdx.x] + sh[tid] - v;
}

// ---------------- CSR fill ----------------
__global__ void fill_kernel(const int* __restrict__ src, const int* __restrict__ dst,
                            const int* __restrict__ rowstart, int* __restrict__ cnt,
                            int* __restrict__ esrc, float* __restrict__ ew,
                            const float* __restrict__ dis, int E) {
    int e = blockIdx.x * blockDim.x + threadIdx.x;
    if (e >= E) return;
    int s = src[e], d = dst[e];
    int pos = rowstart[d] + atomicAdd(&cnt[d], 1);
    esrc[pos] = s;
    ew[pos] = dis[s] * dis[d];
}

// ---------------- d = A_hat * 1 (row sums incl. self loop) ----------------
__global__ void dvec_kernel(const int* __restrict__ rowstart, const float* __restrict__ ew,
                            const float* __restrict__ dis, float* __restrict__ d, int n) {
    int i = blockIdx.x * 256 + threadIdx.x;
    if (i >= n) return;
    float s = dis[i] * dis[i];
    for (int j = rowstart[i]; j < rowstart[i + 1]; ++j) s += ew[j];
    d[i] = s;
}

// ---------------- scaled W transpose: WT[n][k] = bf16(scale?[k] * W[k][n]), zero-padded ----------------
__global__ void wtscale_kernel(const float* __restrict__ W, const float* __restrict__ scale,
                               ushort_t* __restrict__ WT, int K, int N, int KP, int NP) {
    int i = blockIdx.x * 256 + threadIdx.x;
    if (i >= NP * KP) return;
    int n = i / KP, k = i - n * KP;
    float v = (k < K && n < N) ? W[(size_t)k * N + n] : 0.f;
    if (scale && k < K) v *= scale[k];
    WT[i] = f_to_bf(v);
}

// ---------------- c[n] = sum_k shift[k] * W[k][n] ----------------
__global__ void cvec_kernel(const float* __restrict__ W, const float* __restrict__ shift,
                            float* __restrict__ c, int K, int N) {
    int n = blockIdx.x * 256 + threadIdx.x;
    if (n >= N) return;
    float s = 0.f;
    for (int k = 0; k < K; ++k) s += shift[k] * W[(size_t)k * N + n];
    c[n] = s;
}

// ---------------- wave-per-node gathers (pure aggregation) ----------------
// layer 1: x f32 [128] -> bf16 [128]. lane owns 2 cols.
__global__ __launch_bounds__(256) void gather_x(
        const float* __restrict__ in, ushort_t* __restrict__ out,
        const int* __restrict__ rowstart, const int* __restrict__ esrc,
        const float* __restrict__ ew, const float* __restrict__ dis, int nnodes) {
    int gw = (blockIdx.x * 256 + threadIdx.x) >> 6;
    if (gw >= nnodes) return;
    int lane = threadIdx.x & 63;
    int c0 = lane * 2;
    int j0 = rowstart[gw], j1 = rowstart[gw + 1];
    float dn = dis[gw], sw = dn * dn;
    float2 v0 = *(const float2*)(in + (size_t)gw * 128 + c0);
    float a0 = v0.x * sw, a1 = v0.y * sw;
    for (int j = j0; j < j1; ++j) {
        int s = esrc[j];
        float w = ew[j];
        float2 u = *(const float2*)(in + (size_t)s * 128 + c0);
        a0 = fmaf(w, u.x, a0);
        a1 = fmaf(w, u.y, a1);
    }
    unsigned int packed = (unsigned int)f_to_bf(a0) | ((unsigned int)f_to_bf(a1) << 16);
    *(unsigned int*)(out + (size_t)gw * 128 + c0) = packed;
}

// bf16 [512] -> bf16 [512], 8 cols/lane, optional bias+elu (no BN here anymore).
__global__ __launch_bounds__(256) void gather_b8(
        const ushort_t* __restrict__ in, ushort_t* __restrict__ out,
        const int* __restrict__ rowstart, const int* __restrict__ esrc,
        const float* __restrict__ ew, const float* __restrict__ dis,
        const float* __restrict__ bias, int F, int do_elu, int nnodes) {
    int gw = (blockIdx.x * 256 + threadIdx.x) >> 6;
    if (gw >= nnodes) return;
    int lane = threadIdx.x & 63;
    int c0 = lane * 8;
    int j0 = rowstart[gw], j1 = rowstart[gw + 1];
    float dn = dis[gw], sw = dn * dn;
    float acc[8];
    {
        short8 u = *(const short8*)(in + (size_t)gw * 512 + c0);
        #pragma unroll
        for (int k = 0; k < 8; ++k) acc[k] = bf_to_f((ushort_t)u[k]) * sw;
    }
    for (int j = j0; j < j1; ++j) {
        int s = esrc[j];
        float w = ew[j];
        short8 u = *(const short8*)(in + (size_t)s * 512 + c0);
        #pragma unroll
        for (int k = 0; k < 8; ++k) acc[k] = fmaf(w, bf_to_f((ushort_t)u[k]), acc[k]);
    }
    short8 o;
    #pragma unroll
    for (int k = 0; k < 8; ++k) {
        float v = 0.f;
        if (c0 + k < F) {
            v = acc[k] + (bias ? bias[c0 + k] : 0.f);
            if (do_elu) v = v > 0.f ? v : expm1f(v);
        }
        o[k] = (short)f_to_bf(v);
    }
    *(short8*)(out + (size_t)gw * 512 + c0) = o;
}

// layer 4: f32 [64] -> out f32 [50], + bias.
__global__ __launch_bounds__(256) void gather_out(
        const float* __restrict__ in, float* __restrict__ out,
        const int* __restrict__ rowstart, const int* __restrict__ esrc,
        const float* __restrict__ ew, const float* __restrict__ dis,
        const float* __restrict__ bias, int nnodes) {
    int gw = (blockIdx.x * 256 + threadIdx.x) >> 6;
    if (gw >= nnodes) return;
    int lane = threadIdx.x & 63;
    int j0 = rowstart[gw], j1 = rowstart[gw + 1];
    float dn = dis[gw], sw = dn * dn;
    float a = 0.f;
    if (lane < 50) a = in[(size_t)gw * 64 + lane] * sw;
    for (int j = j0; j < j1; ++j) {
        int s = esrc[j];
        float w = ew[j];
        if (lane < 50) a = fmaf(w, in[(size_t)s * 64 + lane], a);
    }
    if (lane < 50) out[(size_t)gw * 50 + lane] = a + bias[lane];
}

// ---------------- MFMA GEMM: C = act(A @ WT^T + bias? + dvec?*cvec?) ----------------
// 128x128 tile, 4 waves 2x2, each 64x64 (4x4 frags), BK=32, global_load_lds staging.
// grid: x = N-tiles (fast, shares A-panel in L2), y = M-tiles.
template <typename TC>
__global__ __launch_bounds__(256) void mfma_gemm(
        const ushort_t* __restrict__ A, const ushort_t* __restrict__ WT,
        const float* __restrict__ bias, const float* __restrict__ cvec,
        const float* __restrict__ dvec,
        TC* __restrict__ C,
        int M, int KP, int N, int CP, int do_elu) {
    __shared__ ushort_t lds[8192];   // [0,4096): A 128x32, [4096,8192): B 128x32
    int bn = blockIdx.x * 128;
    int bm = blockIdx.y * 128;
    int tid = threadIdx.x;
    int lane = tid & 63, wid = tid >> 6;
    int wr = wid >> 1, wc = wid & 1;
    int rl = lane & 15, kg = lane >> 4;
    f32x4 acc[4][4] = {};

    for (int k0 = 0; k0 < KP; k0 += 32) {
        #pragma unroll
        for (int i = 0; i < 2; ++i) {
            int sb = (wid * 2 + i) * 64;      // wave-uniform slot base
            int slot = sb + lane;
            int r = slot >> 2, q = slot & 3;  // row, 16B-quarter
            const ushort_t* ga = A + (size_t)(bm + r) * KP + k0 + q * 8;
            const ushort_t* gb = WT + (size_t)(bn + r) * KP + k0 + q * 8;
#if USE_GLL
            __builtin_amdgcn_global_load_lds(
                (const __attribute__((address_space(1))) unsigned int*)ga,
                (__attribute__((address_space(3))) unsigned int*)&lds[sb * 8], 16, 0, 0);
            __builtin_amdgcn_global_load_lds(
                (const __attribute__((address_space(1))) unsigned int*)gb,
                (__attribute__((address_space(3))) unsigned int*)&lds[4096 + sb * 8], 16, 0, 0);
#else
            *(int4*)&lds[slot * 8] = *(const int4*)ga;
            *(int4*)&lds[4096 + slot * 8] = *(const int4*)gb;
#endif
        }
#if USE_GLL
        asm volatile("s_waitcnt vmcnt(0)" ::: "memory");
#endif
        __syncthreads();
        short8 av[4], bv[4];
        #pragma unroll
        for (int mi = 0; mi < 4; ++mi)
            av[mi] = *(const short8*)&lds[(wr * 64 + mi * 16 + rl) * 32 + kg * 8];
        #pragma unroll
        for (int ni = 0; ni < 4; ++ni)
            bv[ni] = *(const short8*)&lds[4096 + (wc * 64 + ni * 16 + rl) * 32 + kg * 8];
        #pragma unroll
        for (int mi = 0; mi < 4; ++mi)
            #pragma unroll
            for (int ni = 0; ni < 4; ++ni)
                acc[mi][ni] = __builtin_amdgcn_mfma_f32_16x16x32_bf16(
                    av[mi], bv[ni], acc[mi][ni], 0, 0, 0);
        __syncthreads();
    }
    // epilogue: D row=(lane>>4)*4+r, col=lane&15 per frag (m89 layout)
    #pragma unroll
    for (int ni = 0; ni < 4; ++ni) {
        int col = bn + wc * 64 + ni * 16 + rl;
        if (col >= CP) continue;
        float bb = 0.f, cc = 0.f;
        if (col < N) {
            bb = bias ? bias[col] : 0.f;
            cc = cvec ? cvec[col] : 0.f;
        }
        #pragma unroll
        for (int mi = 0; mi < 4; ++mi) {
            #pragma unroll
            for (int r = 0; r < 4; ++r) {
                int row = bm + wr * 64 + mi * 16 + kg * 4 + r;
                if (row >= M) continue;
                float v = 0.f;
                if (col < N) {
                    float dr = dvec ? dvec[row] : 1.f;
                    v = acc[mi][ni][r] + bb + dr * cc;
                    if (do_elu) v = v > 0.f ? v : expm1f(v);
                }
                from_f(C[(size_t)row * CP + col], v);
            }
        }
    }
}

// ---------------- column stats ----------------
#define CS_ROWS 128
__global__ void colstats_kernel(const ushort_t* __restrict__ h, float* __restrict__ sum,
                                float* __restrict__ sumsq, int M, int F, int FP) {
    int r0 = blockIdx.x * CS_ROWS;
    int tid = threadIdx.x;
    float s[4] = {0.f, 0.f, 0.f, 0.f}, q[4] = {0.f, 0.f, 0.f, 0.f};
    int rend = min(r0 + CS_ROWS, M);
    for (int r = r0; r < rend; ++r) {
        #pragma unroll
        for (int j = 0; j < 4; ++j) {
            int c = tid + j * 256;
            if (c < F) {
                float v = bf_to_f(h[(size_t)r * FP + c]);
                s[j] += v;
                q[j] += v * v;
            }
        }
    }
    #pragma unroll
    for (int j = 0; j < 4; ++j) {
        int c = tid + j * 256;
        if (c < F) {
            atomicAdd(&sum[c], s[j]);
            atomicAdd(&sumsq[c], q[j]);
        }
    }
}

// zero pad cols [F, FP) so padded reads are well-defined
__global__ void bnparams_kernel(const float* __restrict__ sum, const float* __restrict__ sumsq,
                                const float* __restrict__ g, const float* __restrict__ be,
                                float* __restrict__ scale, float* __restrict__ shift,
                                int F, int FP, float invN) {
    int c = blockIdx.x * blockDim.x + threadIdx.x;
    if (c >= FP) return;
    if (c >= F) { scale[c] = 0.f; shift[c] = 0.f; return; }
    float m = sum[c] * invN;
    float v = sumsq[c] * invN - m * m;
    if (v < 0.f) v = 0.f;
    float sc = g[c] * rsqrtf(v + BN_EPS);
    scale[c] = sc;
    shift[c] = be[c] - m * sc;
}

extern "C" void kernel_launch(void* const* d_in, const int* in_sizes, int n_in,
                              void* d_out, int out_size, void* d_ws, size_t ws_size,
                              hipStream_t stream) {
    const float* x  = (const float*)d_in[0];
    const int* src  = (const int*)d_in[1];
    const int* dst  = (const int*)d_in[2];
    const float* W1 = (const float*)d_in[3];
    const float* b1 = (const float*)d_in[4];
    const float* g1 = (const float*)d_in[5];
    const float* be1= (const float*)d_in[6];
    const float* W2 = (const float*)d_in[7];
    const float* b2 = (const float*)d_in[8];
    const float* g2 = (const float*)d_in[9];
    const float* be2= (const float*)d_in[10];
    const float* W3 = (const float*)d_in[11];
    const float* b3 = (const float*)d_in[12];
    const float* g3 = (const float*)d_in[13];
    const float* be3= (const float*)d_in[14];
    const float* W4 = (const float*)d_in[15];
    const float* b4 = (const float*)d_in[16];
    float* out = (float*)d_out;

    char* ws = (char*)d_ws;
    int*   deg      = (int*)ws;                          // [0.0,0.2) MiB
    int*   cnt      = deg + NN;                          // [0.2,0.4)
    int*   rowstart = cnt + NN;                          // [0.4,0.6)
    float* dis      = (float*)(rowstart + NN + 1);       // [0.6,0.8)
    float* sum      = (float*)(ws + (800 << 10));        // 4x16KB -> ends 864K
    float* sumsq    = sum + 4096;
    float* scale    = sum + 8192;
    float* shift    = sum + 12288;
    int*   bsum     = (int*)(shift + 4096);              // 864K..866K
    int*   boff     = bsum + 256;
    float* cv       = (float*)(ws + (880 << 10));        // 4KB rank-1 col vec
    int*   esrc     = (int*)(ws + (1 << 20));            // [1.00,2.15) MiB
    float* ew       = (float*)(ws + 2359296);            // [2.25,3.40) MiB
    float* dvec     = (float*)(ws + (3520u << 10));      // [3.44,3.63) MiB, 200KB
    ushort_t* wt1 = (ushort_t*)(ws + (4u << 20));                  // 512x128   128KB
    ushort_t* wt2 = (ushort_t*)(ws + (4u << 20) + (512u << 10));   // 1024x512  1MB
    ushort_t* wt3 = (ushort_t*)(ws + (4u << 20) + (1664u << 10));  // 512x1024  1MB
    ushort_t* wt4 = (ushort_t*)(ws + (4u << 20) + (2816u << 10));  // 128x512   128KB
    char* base = ws + (8u << 20);
    const size_t R50 = 52428800;
    ushort_t* regA  = (ushort_t*)base;                   // aggX/aggH1/t3/t4
    ushort_t* regBC = (ushort_t*)(base + R50);           // h1 -> h2 -> h3

    if (ws_size < (8u << 20) + 3 * R50) return;

    const float invN = 1.0f / (float)NN;
    const int NB = (NN + 255) / 256;
    const int GW = (NN * 64 + 255) / 256;
    const int GM = (NN + 127) / 128;                     // 391 M-tiles

    // ---- CSR build + plain W1 transpose ----
    (void)hipMemsetAsync(deg, 0, 2 * NN * sizeof(int), stream);
    deg_kernel<<<(NE + 255) / 256, 256, 0, stream>>>(dst, deg, NE);
    scan_reduce<<<NB, 256, 0, stream>>>(deg, bsum, dis, NN);
    scan_offsets<<<1, 256, 0, stream>>>(bsum, boff, rowstart, NB, NN);
    scan_final<<<NB, 256, 0, stream>>>(deg, boff, rowstart, NN);
    fill_kernel<<<(NE + 255) / 256, 256, 0, stream>>>(src, dst, rowstart, cnt, esrc, ew, dis, NE);
    dvec_kernel<<<NB, 256, 0, stream>>>(rowstart, ew, dis, dvec, NN);
    wtscale_kernel<<<(512 * 128 + 255) / 256, 256, 0, stream>>>(W1, nullptr, wt1, 128, 500, 128, 512);

    // ---- Layer 1: aggX = A_hat x; h1 = elu(aggX W1 + b1) ----
    gather_x<<<GW, 256, 0, stream>>>(x, regA, rowstart, esrc, ew, dis, NN);
    mfma_gemm<ushort_t><<<dim3(4, GM), 256, 0, stream>>>(
        regA, wt1, b1, nullptr, nullptr, regBC, NN, 128, 500, 512, 1);
    (void)hipMemsetAsync(sum, 0, 8192 * sizeof(float), stream);
    colstats_kernel<<<(NN + CS_ROWS - 1) / CS_ROWS, 256, 0, stream>>>(regBC, sum, sumsq, NN, 500, 512);
    bnparams_kernel<<<2, 256, 0, stream>>>(sum, sumsq, g1, be1, scale, shift, 500, 512, invN);

    // ---- Layer 2: aggH1 = A_hat h1; h2 = elu(aggH1 (scale1*W2) + d*c2 + b2) ----
    wtscale_kernel<<<(1024 * 512 + 255) / 256, 256, 0, stream>>>(W2, scale, wt2, 500, 1000, 512, 1024);
    cvec_kernel<<<4, 256, 0, stream>>>(W2, shift, cv, 500, 1000);
    gather_b8<<<GW, 256, 0, stream>>>(
        regBC, regA, rowstart, esrc, ew, dis, nullptr, 500, 0, NN);
    mfma_gemm<ushort_t><<<dim3(8, GM), 256, 0, stream>>>(
        regA, wt2, b2, cv, dvec, regBC, NN, 512, 1000, 1024, 1);
    (void)hipMemsetAsync(sum, 0, 8192 * sizeof(float), stream);
    colstats_kernel<<<(NN + CS_ROWS - 1) / CS_ROWS, 256, 0, stream>>>(regBC, sum, sumsq, NN, 1000, 1024);
    bnparams_kernel<<<4, 256, 0, stream>>>(sum, sumsq, g2, be2, scale, shift, 1000, 1024, invN);

    // ---- Layer 3: t3 = h2 (scale2*W3) + c3; h3 = elu(A_hat t3 + b3) ----
    wtscale_kernel<<<(512 * 1024 + 255) / 256, 256, 0, stream>>>(W3, scale, wt3, 1000, 500, 1024, 512);
    cvec_kernel<<<2, 256, 0, stream>>>(W3, shift, cv, 1000, 500);
    mfma_gemm<ushort_t><<<dim3(4, GM), 256, 0, stream>>>(
        regBC, wt3, nullptr, cv, nullptr, regA, NN, 1024, 500, 512, 0);
    gather_b8<<<GW, 256, 0, stream>>>(
        regA, regBC, rowstart, esrc, ew, dis, b3, 500, 1, NN);
    (void)hipMemsetAsync(sum, 0, 8192 * sizeof(float), stream);
    colstats_kernel<<<(NN + CS_ROWS - 1) / CS_ROWS, 256, 0, stream>>>(regBC, sum, sumsq, NN, 500, 512);
    bnparams_kernel<<<2, 256, 0, stream>>>(sum, sumsq, g3, be3, scale, shift, 500, 512, invN);

    // ---- Layer 4: t4 = h3 (scale3*W4) + c4 (f32); out = A_hat t4 + b4 ----
    wtscale_kernel<<<(128 * 512 + 255) / 256, 256, 0, stream>>>(W4, scale, wt4, 500, 50, 512, 128);
    cvec_kernel<<<1, 256, 0, stream>>>(W4, shift, cv, 500, 50);
    float* t4 = (float*)regA;
    mfma_gemm<float><<<dim3(1, GM), 256, 0, stream>>>(
        regBC, wt4, nullptr, cv, nullptr, t4, NN, 512, 50, 64, 0);
    gather_out<<<GW, 256, 0, stream>>>(t4, out, rowstart, esrc, ew, dis, b4, NN);
}